// Round 1
// baseline (367.390 us; speedup 1.0000x reference)
//
#include <hip/hip_runtime.h>
#include <hip/hip_bf16.h>

// SelfAttention: out = softmax((xWq^T+bq)(xWk^T+bk)^T / 32) (xWv^T+bv)
// B=4, S=2048, D=1024. All GEMMs: bf16 MFMA 16x16x32, fp32 accumulate.
// ws layout (bytes, total ~90.2 MB):
//   xb   [8192*1024] bf16
//   wqb,wkb,wvb [1024*1024] bf16 each
//   qb,kb [8192*1024] bf16
//   vtb  [4][1024][2048] bf16 (V transposed per batch for NT PV gemm)
//   sc   [2048*2048] fp32 (per-batch scores, reused; softmax writes bf16 P
//        in-place at row stride 4096 bf16 elements)

typedef __hip_bfloat16 bf16;
typedef __attribute__((ext_vector_type(8))) short bf16x8;
typedef __attribute__((ext_vector_type(4))) float f32x4;
typedef __attribute__((ext_vector_type(4))) short short4v;

__global__ __launch_bounds__(256)
void cast_f32_to_bf16(const float* __restrict__ in, bf16* __restrict__ out, long n) {
  long i = ((long)blockIdx.x * blockDim.x + threadIdx.x) * 4;
  long stride = (long)gridDim.x * blockDim.x * 4;
  for (; i < n; i += stride) {
    float4 f = *(const float4*)(in + i);
    bf16 tmp[4];
    tmp[0] = __float2bfloat16(f.x);
    tmp[1] = __float2bfloat16(f.y);
    tmp[2] = __float2bfloat16(f.z);
    tmp[3] = __float2bfloat16(f.w);
    *(short4v*)(out + i) = *(short4v*)tmp;
  }
}

// C = scale * (A @ Bt^T) + bias.  A: [M][lda] bf16 row-major (cols 0..K-1),
// Bt: [N][ldb] bf16 row-major.  Tile 128x128, 4 waves (2x2), BK=64.
// OMODE 0: C fp32 [M][ldc].  1: C bf16 [M][ldc].  2: C bf16 transposed
// per-batch: C[(m/seq)*N*seq + n*seq + (m%seq)].
template<int OMODE>
__global__ __launch_bounds__(256)
void gemm_bt(const bf16* __restrict__ A, const bf16* __restrict__ Bt,
             const float* __restrict__ bias, void* __restrict__ Cout,
             int M, int N, int K, int lda, int ldb, int ldc,
             float scale, int seq)
{
  // +8 bf16 pad (16B) keeps 16B alignment per row, row stride 144B = 9*16B:
  // fragment ds_read_b128 hits banks 4r%32 across the 16-lane group -> 2-way (free).
  __shared__ __align__(16) bf16 As[128][72];
  __shared__ __align__(16) bf16 Bs[128][72];
  const int tid = threadIdx.x;
  const long bm = (long)blockIdx.x * 128;
  const long bn = (long)blockIdx.y * 128;
  const int wid = tid >> 6;
  const int lane = tid & 63;
  const int wr = (wid >> 1) * 64;   // wave row offset in tile
  const int wc = (wid & 1) * 64;    // wave col offset in tile
  const int l15 = lane & 15;
  const int kg = lane >> 4;         // 0..3

  f32x4 acc[4][4];
#pragma unroll
  for (int m = 0; m < 4; ++m)
#pragma unroll
    for (int n = 0; n < 4; ++n)
      acc[m][n] = (f32x4){0.f, 0.f, 0.f, 0.f};

  for (int k0 = 0; k0 < K; k0 += 64) {
    // stage 128x64 bf16 of A and Bt: 1024 16B-chunks each, 256 thr x 4
#pragma unroll
    for (int i = 0; i < 4; ++i) {
      const int idx = tid + i * 256;
      const int r = idx >> 3;
      const int c = (idx & 7) << 3;
      *(bf16x8*)&As[r][c] = *(const bf16x8*)(A + (bm + r) * lda + k0 + c);
      *(bf16x8*)&Bs[r][c] = *(const bf16x8*)(Bt + (bn + r) * ldb + k0 + c);
    }
    __syncthreads();
#pragma unroll
    for (int kk = 0; kk < 2; ++kk) {
      bf16x8 af[4], bfr[4];
#pragma unroll
      for (int m = 0; m < 4; ++m)
        af[m] = *(const bf16x8*)&As[wr + m * 16 + l15][kk * 32 + kg * 8];
#pragma unroll
      for (int n = 0; n < 4; ++n)
        bfr[n] = *(const bf16x8*)&Bs[wc + n * 16 + l15][kk * 32 + kg * 8];
#pragma unroll
      for (int m = 0; m < 4; ++m)
#pragma unroll
        for (int n = 0; n < 4; ++n)
          acc[m][n] = __builtin_amdgcn_mfma_f32_16x16x32_bf16(
              af[m], bfr[n], acc[m][n], 0, 0, 0);
    }
    __syncthreads();
  }

  // C/D layout (m89-verified): frag row = kg*4 + r, col = l15
#pragma unroll
  for (int m = 0; m < 4; ++m) {
    const long row0 = bm + wr + m * 16 + kg * 4;
#pragma unroll
    for (int n = 0; n < 4; ++n) {
      const long col = bn + wc + n * 16 + l15;
      const float bias_v = bias ? bias[col] : 0.f;
      if constexpr (OMODE == 0) {
        float* C = (float*)Cout;
#pragma unroll
        for (int r = 0; r < 4; ++r)
          C[(row0 + r) * ldc + col] = acc[m][n][r] * scale + bias_v;
      } else if constexpr (OMODE == 1) {
        bf16* C = (bf16*)Cout;
#pragma unroll
        for (int r = 0; r < 4; ++r)
          C[(row0 + r) * ldc + col] = __float2bfloat16(acc[m][n][r] * scale + bias_v);
      } else {
        bf16* C = (bf16*)Cout;
        const long bb = row0 / seq;
        const long s0 = row0 % seq;   // multiple of 4 -> 8B-aligned store
        bf16 tmp[4];
#pragma unroll
        for (int r = 0; r < 4; ++r)
          tmp[r] = __float2bfloat16(acc[m][n][r] * scale + bias_v);
        *(short4v*)&C[(bb * (long)N + col) * seq + s0] = *(short4v*)tmp;
      }
    }
  }
}

// One block per row of 2048 fp32 scores: softmax, write bf16 P in-place
// (bf16 row occupies first half of the fp32 row's bytes; all reads complete
// before the first __syncthreads, writes only after -> no intra-row race;
// rows are block-private -> no inter-row race).
__global__ __launch_bounds__(256)
void softmax_inplace_bf16(float* __restrict__ S, int ncols /*2048*/) {
  float* row = S + (size_t)blockIdx.x * ncols;
  const int tid = threadIdx.x;
  __shared__ float redA[4], redB[4];
  float v[8];
  float mx = -1e30f;
#pragma unroll
  for (int i = 0; i < 8; ++i) {
    v[i] = row[tid + (i << 8)];
    mx = fmaxf(mx, v[i]);
  }
#pragma unroll
  for (int o = 32; o; o >>= 1) mx = fmaxf(mx, __shfl_xor(mx, o));
  if ((tid & 63) == 0) redA[tid >> 6] = mx;
  __syncthreads();
  mx = fmaxf(fmaxf(redA[0], redA[1]), fmaxf(redA[2], redA[3]));
  float sum = 0.f;
#pragma unroll
  for (int i = 0; i < 8; ++i) {
    v[i] = __expf(v[i] - mx);
    sum += v[i];
  }
#pragma unroll
  for (int o = 32; o; o >>= 1) sum += __shfl_xor(sum, o);
  if ((tid & 63) == 0) redB[tid >> 6] = sum;
  __syncthreads();
  sum = redB[0] + redB[1] + redB[2] + redB[3];
  const float inv = 1.f / sum;
  bf16* po = (bf16*)row;
#pragma unroll
  for (int i = 0; i < 8; ++i)
    po[tid + (i << 8)] = __float2bfloat16(v[i] * inv);
}

extern "C" void kernel_launch(void* const* d_in, const int* in_sizes, int n_in,
                              void* d_out, int out_size, void* d_ws, size_t ws_size,
                              hipStream_t stream) {
  const float* x  = (const float*)d_in[0];
  const float* Wq = (const float*)d_in[1];
  const float* bq = (const float*)d_in[2];
  const float* Wk = (const float*)d_in[3];
  const float* bk = (const float*)d_in[4];
  const float* Wv = (const float*)d_in[5];
  const float* bv = (const float*)d_in[6];
  float* out = (float*)d_out;

  const int B = 4, S = 2048, D = 1024;
  const int M = B * S;  // 8192

  bf16* xb  = (bf16*)d_ws;
  bf16* wqb = xb + (size_t)M * D;
  bf16* wkb = wqb + (size_t)D * D;
  bf16* wvb = wkb + (size_t)D * D;
  bf16* qb  = wvb + (size_t)D * D;
  bf16* kb  = qb + (size_t)M * D;
  bf16* vtb = kb + (size_t)M * D;
  float* sc = (float*)(vtb + (size_t)M * D);  // 2048*2048 fp32, reused per batch

  // ---- cast inputs to bf16 ----
  cast_f32_to_bf16<<<dim3(2048), 256, 0, stream>>>(x, xb, (long)M * D);
  cast_f32_to_bf16<<<dim3(512), 256, 0, stream>>>(Wq, wqb, (long)D * D);
  cast_f32_to_bf16<<<dim3(512), 256, 0, stream>>>(Wk, wkb, (long)D * D);
  cast_f32_to_bf16<<<dim3(512), 256, 0, stream>>>(Wv, wvb, (long)D * D);

  // ---- QKV projections ----
  dim3 gp(M / 128, D / 128);
  gemm_bt<1><<<gp, 256, 0, stream>>>(xb, wqb, bq, qb, M, D, D, D, D, D, 1.f, 0);
  gemm_bt<1><<<gp, 256, 0, stream>>>(xb, wkb, bk, kb, M, D, D, D, D, D, 1.f, 0);
  gemm_bt<2><<<gp, 256, 0, stream>>>(xb, wvb, bv, vtb, M, D, D, D, D, D, 1.f, S);

  // ---- attention, per batch (scores buffer reused; same stream serializes) ----
  const float iscale = 1.0f / 32.0f;  // 1/sqrt(1024)
  for (int b = 0; b < B; ++b) {
    const bf16* qB = qb + (size_t)b * S * D;
    const bf16* kB = kb + (size_t)b * S * D;
    const bf16* vB = vtb + (size_t)b * S * D;  // [D][S] row-major
    float* oB = out + (size_t)b * S * D;
    gemm_bt<0><<<dim3(S / 128, S / 128), 256, 0, stream>>>(
        qB, kB, nullptr, sc, S, S, D, D, D, S, iscale, 0);
    softmax_inplace_bf16<<<S, 256, 0, stream>>>(sc, S);
    // P: bf16 at row stride 4096 elements (in-place over sc)
    gemm_bt<0><<<dim3(S / 128, D / 128), 256, 0, stream>>>(
        (const bf16*)sc, vB, nullptr, oB, S, D, S, 2 * S, S, D, 1.f, 0);
  }
}

// Round 2
// 178.689 us; speedup vs baseline: 2.0560x; 2.0560x over previous
//
#include <hip/hip_runtime.h>
#include <hip/hip_bf16.h>

// SelfAttention B=4 S=2048 D=1024:
//   out = softmax((xWq^T+bq)(xWk^T+bk)^T / 32) (xWv^T+bv)
// bf16 MFMA 16x16x32, fp32 accumulate, fp32 scores for softmax.
// ws layout: xb[8192*1024]bf16 | wqb,wkb,wvb[1024*1024]bf16 (contig) |
//            qb,kb[8192*1024]bf16 (contig) | vtb[4][1024][2048]bf16 |
//            sc[nb][2048*2048]fp32 (nb from ws_size; softmax writes bf16 P
//            in-place at row stride 4096 bf16)

typedef __hip_bfloat16 bf16;
typedef __attribute__((ext_vector_type(8))) short bf16x8;
typedef __attribute__((ext_vector_type(4))) float f32x4;
typedef __attribute__((ext_vector_type(4))) short short4v;

__device__ __forceinline__ void gload16(const void* g, void* l) {
  __builtin_amdgcn_global_load_lds(
      (const __attribute__((address_space(1))) void*)g,
      (__attribute__((address_space(3))) void*)l, 16, 0, 0);
}

__global__ __launch_bounds__(256)
void cast_f32_to_bf16(const float* __restrict__ in, bf16* __restrict__ out) {
  long i = ((long)blockIdx.x * blockDim.x + threadIdx.x) * 4;
  float4 f = *(const float4*)(in + i);
  bf16 tmp[4];
  tmp[0] = __float2bfloat16(f.x);
  tmp[1] = __float2bfloat16(f.y);
  tmp[2] = __float2bfloat16(f.z);
  tmp[3] = __float2bfloat16(f.w);
  *(short4v*)(out + i) = *(short4v*)tmp;
}

// Tile 128x128, 4 waves (2x2, each 64x64), BK=64, global_load_lds staging
// with XOR swizzle: LDS linear [128][64] bf16; 16B chunk (r, j) stored at
// chunk index r*8 + (j ^ (r&7)); staging pre-swizzles the GLOBAL source
// address (rule 21), ds_read applies the same XOR.
// OMODE 0: C = scale*(A @ Bt^T), fp32, [.][ldc] at Cout + z*sC.
// OMODE 3: QKV-combo. A=xb (sA=0), Bt=wqb base (sB=D*D), z in {0,1,2}:
//   z<2: bf16 [8192][1024] at Cout + z*8192*1024 (+bias)   [Q,K]
//   z=2: bf16 transposed vtb[(b*1024+col)*2048 + s] (+bias) [V^T per batch]
template<int OMODE>
__global__ __launch_bounds__(256, 3)
void gemm_bt(const bf16* __restrict__ A, const bf16* __restrict__ Bt,
             const float* __restrict__ b0, const float* __restrict__ b1,
             const float* __restrict__ b2, void* __restrict__ Cout,
             int K, int lda, int ldb, int ldc, float scale,
             long sA, long sB, long sC)
{
  __shared__ __align__(16) bf16 As[128 * 64];
  __shared__ __align__(16) bf16 Bs[128 * 64];
  const int tid = threadIdx.x;
  const int z = blockIdx.z;
  const bf16* Ab = A + (long)z * sA;
  const bf16* Bb = Bt + (long)z * sB;
  const long bm = (long)blockIdx.x * 128;
  const long bn = (long)blockIdx.y * 128;
  const int wid = tid >> 6;
  const int lane = tid & 63;
  const int wr = (wid >> 1) * 64;
  const int wc = (wid & 1) * 64;
  const int l15 = lane & 15;
  const int kg = lane >> 4;

  // per-thread staging source (chunk c = i*256 + tid): row r=c>>3, swizzled
  // col j = (c&7) ^ (r&7); LDS dest is the wave-uniform linear chunk base.
  f32x4 acc[4][4];
#pragma unroll
  for (int m = 0; m < 4; ++m)
#pragma unroll
    for (int n = 0; n < 4; ++n)
      acc[m][n] = (f32x4){0.f, 0.f, 0.f, 0.f};

  for (int k0 = 0; k0 < K; k0 += 64) {
#pragma unroll
    for (int i = 0; i < 4; ++i) {
      const int c = (i << 8) + tid;
      const int r = c >> 3;
      const int j = (c & 7) ^ (r & 7);
      const int ldsch = (i << 8) + (wid << 6);  // wave-uniform chunk index
      gload16(Ab + (long)(bm + r) * lda + k0 + (j << 3), (bf16*)As + ldsch * 8);
      gload16(Bb + (long)(bn + r) * ldb + k0 + (j << 3), (bf16*)Bs + ldsch * 8);
    }
    __syncthreads();  // drains vmcnt before use
#pragma unroll
    for (int kk = 0; kk < 2; ++kk) {
      const int jp = ((kk << 2) + kg) ^ (l15 & 7);  // row&7 == l15&7 here
      bf16x8 af[4], bfv[4];
#pragma unroll
      for (int m = 0; m < 4; ++m)
        af[m] = *(const bf16x8*)&As[(wr + (m << 4) + l15) * 64 + (jp << 3)];
#pragma unroll
      for (int n = 0; n < 4; ++n)
        bfv[n] = *(const bf16x8*)&Bs[(wc + (n << 4) + l15) * 64 + (jp << 3)];
#pragma unroll
      for (int m = 0; m < 4; ++m)
#pragma unroll
        for (int n = 0; n < 4; ++n)
          acc[m][n] = __builtin_amdgcn_mfma_f32_16x16x32_bf16(
              af[m], bfv[n], acc[m][n], 0, 0, 0);
    }
    __syncthreads();
  }

  // C/D layout (m89): frag row = kg*4 + r, col = l15
#pragma unroll
  for (int m = 0; m < 4; ++m) {
    const long row0 = bm + wr + (m << 4) + kg * 4;
#pragma unroll
    for (int n = 0; n < 4; ++n) {
      const long col = bn + wc + (n << 4) + l15;
      if constexpr (OMODE == 0) {
        float* C = (float*)Cout + z * sC;
#pragma unroll
        for (int r = 0; r < 4; ++r)
          C[(row0 + r) * ldc + col] = acc[m][n][r] * scale;
      } else {  // OMODE 3: QKV combo
        const float* bias = (z == 0) ? b0 : (z == 1) ? b1 : b2;
        const float bias_v = bias[col];
        if (z < 2) {
          bf16* C = (bf16*)Cout + (long)z * 8192 * 1024;
#pragma unroll
          for (int r = 0; r < 4; ++r)
            C[(row0 + r) * 1024 + col] = __float2bfloat16(acc[m][n][r] + bias_v);
        } else {
          bf16* C = (bf16*)Cout + 2L * 8192 * 1024;  // vtb
          const long bb = row0 >> 11;       // row0 / 2048
          const long s0 = row0 & 2047;      // multiple of 4 -> 8B aligned
          bf16 tmp[4];
#pragma unroll
          for (int r = 0; r < 4; ++r)
            tmp[r] = __float2bfloat16(acc[m][n][r] + bias_v);
          *(short4v*)&C[(bb * 1024 + col) * 2048 + s0] = *(short4v*)tmp;
        }
      }
    }
  }
}

// One block per 2048-col fp32 score row: softmax, bf16 P written in-place
// (all reads complete before first barrier; writes after second -> no race).
__global__ __launch_bounds__(256)
void softmax_inplace_bf16(float* __restrict__ S) {
  float* row = S + (size_t)blockIdx.x * 2048;
  const int tid = threadIdx.x;
  __shared__ float redA[4], redB[4];
  float v[8];
  float mx = -1e30f;
#pragma unroll
  for (int i = 0; i < 8; ++i) {
    v[i] = row[tid + (i << 8)];
    mx = fmaxf(mx, v[i]);
  }
#pragma unroll
  for (int o = 32; o; o >>= 1) mx = fmaxf(mx, __shfl_xor(mx, o));
  if ((tid & 63) == 0) redA[tid >> 6] = mx;
  __syncthreads();
  mx = fmaxf(fmaxf(redA[0], redA[1]), fmaxf(redA[2], redA[3]));
  float sum = 0.f;
#pragma unroll
  for (int i = 0; i < 8; ++i) {
    v[i] = __expf(v[i] - mx);
    sum += v[i];
  }
#pragma unroll
  for (int o = 32; o; o >>= 1) sum += __shfl_xor(sum, o);
  if ((tid & 63) == 0) redB[tid >> 6] = sum;
  __syncthreads();
  sum = redB[0] + redB[1] + redB[2] + redB[3];
  const float inv = 1.f / sum;
  bf16* po = (bf16*)row;
#pragma unroll
  for (int i = 0; i < 8; ++i)
    po[tid + (i << 8)] = __float2bfloat16(v[i] * inv);
}

extern "C" void kernel_launch(void* const* d_in, const int* in_sizes, int n_in,
                              void* d_out, int out_size, void* d_ws, size_t ws_size,
                              hipStream_t stream) {
  const float* x  = (const float*)d_in[0];
  const float* Wq = (const float*)d_in[1];
  const float* bq = (const float*)d_in[2];
  const float* Wk = (const float*)d_in[3];
  const float* bk = (const float*)d_in[4];
  const float* Wv = (const float*)d_in[5];
  const float* bv = (const float*)d_in[6];
  float* out = (float*)d_out;

  const int B = 4, S = 2048, D = 1024;
  const int M = B * S;  // 8192

  bf16* xb  = (bf16*)d_ws;
  bf16* wqb = xb + (size_t)M * D;          // wqb,wkb,wvb contiguous
  bf16* qb  = wqb + 3 * (size_t)D * D;     // qb,kb contiguous, then vtb
  bf16* kb  = qb + (size_t)M * D;
  bf16* vtb = kb + (size_t)M * D;
  float* sc = (float*)(vtb + (size_t)M * D);

  // score buffers: as many batches at once as ws allows (deterministic:
  // ws_size is fixed by the harness)
  size_t avail = ws_size - ((size_t)((char*)sc - (char*)d_ws));
  int nb = (int)(avail / ((size_t)S * S * 4));
  if (nb > B) nb = B;
  if (nb < 1) nb = 1;  // round-0 footprint (1 buffer) is known to fit

  // ---- casts ----
  cast_f32_to_bf16<<<dim3(M * D / 1024), 256, 0, stream>>>(x, xb);
  cast_f32_to_bf16<<<dim3(D * D / 1024), 256, 0, stream>>>(Wq, wqb);
  cast_f32_to_bf16<<<dim3(D * D / 1024), 256, 0, stream>>>(Wk, wqb + (size_t)D * D);
  cast_f32_to_bf16<<<dim3(D * D / 1024), 256, 0, stream>>>(Wv, wqb + 2 * (size_t)D * D);

  // ---- fused QKV projection (z: 0=Q, 1=K, 2=V^T) ----
  gemm_bt<3><<<dim3(M / 128, D / 128, 3), 256, 0, stream>>>(
      xb, wqb, bq, bk, bv, qb, D, D, D, D, 1.f, 0, (long)D * D, 0);

  // ---- attention, nb batches per group ----
  const float iscale = 1.0f / 32.0f;  // 1/sqrt(1024)
  for (int g = 0; g < B; g += nb) {
    const int gn = (g + nb <= B) ? nb : (B - g);
    gemm_bt<0><<<dim3(S / 128, S / 128, gn), 256, 0, stream>>>(
        qb + (size_t)g * S * D, kb + (size_t)g * S * D, nullptr, nullptr, nullptr,
        sc, D, D, D, S, iscale, (long)S * D, (long)S * D, (long)S * S);
    softmax_inplace_bf16<<<dim3(gn * S), 256, 0, stream>>>(sc);
    // P bf16 in-place at row stride 4096 elements
    gemm_bt<0><<<dim3(S / 128, D / 128, gn), 256, 0, stream>>>(
        (const bf16*)sc, vtb + (size_t)g * D * S, nullptr, nullptr, nullptr,
        out + (size_t)g * S * D, S, 2 * S, S, D, 1.f,
        2L * S * S, (long)D * S, (long)S * D);
  }
}